// Round 3
// baseline (187.531 us; speedup 1.0000x reference)
//
#include <hip/hip_runtime.h>

// Problem constants (B=2, N=2048, d_model=1024, H=16, D=64)
#define DMODEL 1024
#define NSEQ   2048
#define BSZ    2
#define NH     16
#define HD     64
#define MROWS  (BSZ*NSEQ)   // 4096

using short8 = __attribute__((ext_vector_type(8))) short;
using f32x4  = __attribute__((ext_vector_type(4))) float;

__device__ __forceinline__ short f2b(float f) {
  unsigned u = __builtin_bit_cast(unsigned, f);
  u += 0x7fffu + ((u >> 16) & 1u);          // RNE
  return (short)(u >> 16);
}
__device__ __forceinline__ float b2f(short s) {
  unsigned u = ((unsigned)(unsigned short)s) << 16;
  return __builtin_bit_cast(float, u);
}

__device__ __forceinline__ void load_lds16(const void* g, void* l) {
  __builtin_amdgcn_global_load_lds((const __attribute__((address_space(1))) unsigned int*)g,
                                   (__attribute__((address_space(3))) unsigned int*)l,
                                   16, 0, 0);
}

// ---------------- fp32 -> bf16 conversion ----------------
__global__ void cvt_bf16(const float* __restrict__ in, short* __restrict__ out, int n4) {
  int i = blockIdx.x * blockDim.x + threadIdx.x;
  int stride = gridDim.x * blockDim.x;
  for (; i < n4; i += stride) {
    float4 v = reinterpret_cast<const float4*>(in)[i];
    short4 r;
    r.x = f2b(v.x); r.y = f2b(v.y); r.z = f2b(v.z); r.w = f2b(v.w);
    reinterpret_cast<short4*>(out)[i] = r;
  }
}

// ---------------- RoPE cos/sin table (fp32, precise) ----------------
__global__ void rope_table(const int* __restrict__ pos, float* __restrict__ cs) {
  int idx = blockIdx.x * blockDim.x + threadIdx.x;   // n*32 + p
  if (idx >= NSEQ * 32) return;
  int n = idx >> 5, p = idx & 31;
  float inv = powf(10000.0f, -(float)(2 * p) / 64.0f);
  float ang = (float)pos[n] * inv;
  cs[idx * 2]     = cosf(ang);
  cs[idx * 2 + 1] = sinf(ang);
}

// ---------------- shared 128x128x(K=1024) bf16 MFMA GEMM core ----------------
// C[m][j] = sum_i A[m][i] * W[j][i]  (both row-major along K, NT form)
// 4 waves, each owns a 64x64 quadrant (4x4 grid of 16x16x32 mfma).
// LDS tiles [128][64] bf16, T2 XOR-swizzle: byte ^= ((row&7)<<4), staged via
// global_load_lds (linear dest) with pre-swizzled global source (rule #21).
__device__ __forceinline__ void gemm_core(const short* __restrict__ A,
                                          const short* __restrict__ Bw,
                                          int arow0, int bcol0,
                                          short* As, short* Bs,
                                          f32x4 (&acc)[4][4]) {
  const int t = threadIdx.x;
  const int l = t & 63;
  const int w = t >> 6;
  const int wr = (w >> 1) * 64;
  const int wc = (w & 1) * 64;
  const int srow = t >> 3;   // 0..31
  const int sc8  = t & 7;

#pragma unroll
  for (int mi = 0; mi < 4; ++mi)
#pragma unroll
    for (int ni = 0; ni < 4; ++ni) acc[mi][ni] = f32x4{0.f, 0.f, 0.f, 0.f};

  for (int kt = 0; kt < DMODEL / 64; ++kt) {
#pragma unroll
    for (int is = 0; is < 4; ++is) {
      int row = srow + is * 32;
      int c8 = sc8 ^ (row & 7);                    // pre-swizzled source
      load_lds16(A  + (size_t)(arow0 + row) * DMODEL + kt * 64 + c8 * 8,
                 As + w * 512 + is * 2048);
      load_lds16(Bw + (size_t)(bcol0 + row) * DMODEL + kt * 64 + c8 * 8,
                 Bs + w * 512 + is * 2048);
    }
    asm volatile("s_waitcnt vmcnt(0)" ::: "memory");
    __syncthreads();

#pragma unroll
    for (int ks = 0; ks < 2; ++ks) {
      short8 af[4], bf[4];
      const int cb = ks * 64 + ((l >> 4) * 16);    // byte col within 128B row
#pragma unroll
      for (int mi = 0; mi < 4; ++mi) {
        int rr = wr + mi * 16 + (l & 15);
        af[mi] = *reinterpret_cast<const short8*>(
            reinterpret_cast<const char*>(As) + rr * 128 + (cb ^ ((rr & 7) << 4)));
      }
#pragma unroll
      for (int ni = 0; ni < 4; ++ni) {
        int rr = wc + ni * 16 + (l & 15);
        bf[ni] = *reinterpret_cast<const short8*>(
            reinterpret_cast<const char*>(Bs) + rr * 128 + (cb ^ ((rr & 7) << 4)));
      }
#pragma unroll
      for (int mi = 0; mi < 4; ++mi)
#pragma unroll
        for (int ni = 0; ni < 4; ++ni)
          acc[mi][ni] = __builtin_amdgcn_mfma_f32_16x16x32_bf16(af[mi], bf[ni], acc[mi][ni], 0, 0, 0);
    }
    __syncthreads();
  }
}

// ---------------- QKV projection + fused RoPE epilogue ----------------
// grid (32, 24): y/8 selects proj (0=Q,1=K,2=V), y%8 selects 128-col tile.
// Q,K -> bf16 (B,H,N,D) with RoPE (Q pre-scaled by 1/8 = exact in bf16).
// V   -> bf16 (B,H,D,N)  (transposed so PV B-fragments read contiguously).
__global__ __launch_bounds__(256) void gemm_qkv(
    const short* __restrict__ xb,
    const short* __restrict__ wq, const short* __restrict__ wk, const short* __restrict__ wv,
    const float* __restrict__ cs,
    short* __restrict__ qb, short* __restrict__ kb, short* __restrict__ vt) {
  __shared__ short As[128 * 64];
  __shared__ short Bs[128 * 64];
  const int t = threadIdx.x;
  const int l = t & 63;
  const int w = t >> 6;
  const int wr = (w >> 1) * 64;
  const int wc = (w & 1) * 64;
  const int bx = blockIdx.x;
  const int by = blockIdx.y;
  const int proj = by >> 3;
  const int bcol0 = (by & 7) * 128;
  const int arow0 = bx * 128;
  const short* Bw = (proj == 0) ? wq : (proj == 1) ? wk : wv;

  f32x4 acc[4][4];
  gemm_core(xb, Bw, arow0, bcol0, As, Bs, acc);

#pragma unroll
  for (int mi = 0; mi < 4; ++mi) {
#pragma unroll
    for (int ni = 0; ni < 4; ++ni) {
#pragma unroll
      for (int r = 0; r < 4; ++r) {
        float v = acc[mi][ni][r];
        int m = arow0 + wr + mi * 16 + ((l >> 4) << 2) + r;
        int j = bcol0 + wc + ni * 16 + (l & 15);
        int n = m & (NSEQ - 1);
        int b = m >> 11;
        int h = j >> 6, d = j & 63, p = d >> 1;
        float pv = __shfl_xor(v, 1);              // partner column (j^1), same row
        if (proj < 2) {
          float c = cs[(n * 32 + p) * 2];
          float s = cs[(n * 32 + p) * 2 + 1];
          float res = (d & 1) ? (pv * s + v * c) : (v * c - pv * s);
          if (proj == 0) res *= 0.125f;           // fold 1/sqrt(D); exact pow2 in bf16
          short* dst = (proj == 0) ? qb : kb;
          dst[(((size_t)(b * NH + h)) * NSEQ + n) * HD + d] = f2b(res);
        } else {
          vt[(((size_t)(b * NH + h)) * HD + d) * NSEQ + n] = f2b(v);
        }
      }
    }
  }
}

// ---------------- output projection ----------------
__global__ __launch_bounds__(256) void gemm_out(
    const short* __restrict__ ob, const short* __restrict__ wo, float* __restrict__ out) {
  __shared__ short As[128 * 64];
  __shared__ short Bs[128 * 64];
  const int t = threadIdx.x;
  const int l = t & 63;
  const int w = t >> 6;
  const int wr = (w >> 1) * 64;
  const int wc = (w & 1) * 64;
  const int arow0 = blockIdx.x * 128;
  const int bcol0 = blockIdx.y * 128;

  f32x4 acc[4][4];
  gemm_core(ob, wo, arow0, bcol0, As, Bs, acc);

#pragma unroll
  for (int mi = 0; mi < 4; ++mi) {
#pragma unroll
    for (int ni = 0; ni < 4; ++ni) {
#pragma unroll
      for (int r = 0; r < 4; ++r) {
        int m = arow0 + wr + mi * 16 + ((l >> 4) << 2) + r;
        int j = bcol0 + wc + ni * 16 + (l & 15);
        out[(size_t)m * DMODEL + j] = acc[mi][ni][r];
      }
    }
  }
}

// ---------------- flash attention (causal, online softmax) ----------------
// grid (B*H=32, N/64=32), 256 threads = 4 waves. Wave w owns Q rows
// q0+w*16 .. +15. Per KV tile (64 keys): S = Q*K^T via mfma (Q pre-scaled),
// fp32 online softmax, P->bf16 via per-wave swizzled LDS, PV via V^T tiles.
__global__ __launch_bounds__(256) void attn(
    const short* __restrict__ qb, const short* __restrict__ kb,
    const short* __restrict__ vt, short* __restrict__ ob) {
  __shared__ short Ks[64 * 64];
  __shared__ short Vs[64 * 64];
  __shared__ short Ps[4][16 * 64];
  const int t = threadIdx.x;
  const int l = t & 63;
  const int w = t >> 6;
  const int bh = blockIdx.x;
  const int q0 = blockIdx.y * 64;
  const short* Q  = qb + (size_t)bh * NSEQ * HD;
  const short* Kg = kb + (size_t)bh * NSEQ * HD;
  const short* Vg = vt + (size_t)bh * HD * NSEQ;

  // Q fragments in registers (16 rows x 64 d per wave)
  short8 qf[2];
  {
    int qrow = q0 + w * 16 + (l & 15);
#pragma unroll
    for (int ks = 0; ks < 2; ++ks)
      qf[ks] = *reinterpret_cast<const short8*>(Q + (size_t)qrow * HD + ks * 32 + (l >> 4) * 8);
  }

  f32x4 ao[4];
#pragma unroll
  for (int dt = 0; dt < 4; ++dt) ao[dt] = f32x4{0.f, 0.f, 0.f, 0.f};
  float mrow[4], lrow[4];
#pragma unroll
  for (int r = 0; r < 4; ++r) { mrow[r] = -1e30f; lrow[r] = 0.f; }

  const int nt = q0 / 64;                 // last (diagonal) tile index
  const int srow = t >> 3;                // 0..31
  const int sc8  = t & 7;
  const int irow = (l >> 4) << 2;

  for (int tile = 0; tile <= nt; ++tile) {
    const int j0 = tile * 64;
#pragma unroll
    for (int is = 0; is < 2; ++is) {
      int row = srow + is * 32;
      int c8 = sc8 ^ (row & 7);
      load_lds16(Kg + (size_t)(j0 + row) * HD + c8 * 8, Ks + w * 512 + is * 2048);
      load_lds16(Vg + (size_t)row * NSEQ + j0 + c8 * 8, Vs + w * 512 + is * 2048);
    }
    asm volatile("s_waitcnt vmcnt(0)" ::: "memory");
    __syncthreads();

    // S = Q K^T (already scaled by 1/8 via Q)
    f32x4 sc[4];
#pragma unroll
    for (int jt = 0; jt < 4; ++jt) sc[jt] = f32x4{0.f, 0.f, 0.f, 0.f};
#pragma unroll
    for (int ks = 0; ks < 2; ++ks) {
      const int cb = ks * 64 + ((l >> 4) * 16);
#pragma unroll
      for (int jt = 0; jt < 4; ++jt) {
        int kr = jt * 16 + (l & 15);
        short8 kf = *reinterpret_cast<const short8*>(
            reinterpret_cast<const char*>(Ks) + kr * 128 + (cb ^ ((kr & 7) << 4)));
        sc[jt] = __builtin_amdgcn_mfma_f32_16x16x32_bf16(qf[ks], kf, sc[jt], 0, 0, 0);
      }
    }

    if (tile == nt) {                      // causal mask on diagonal tile
#pragma unroll
      for (int jt = 0; jt < 4; ++jt)
#pragma unroll
        for (int r = 0; r < 4; ++r) {
          int i_rel = w * 16 + irow + r;
          int jj = jt * 16 + (l & 15);
          if (jj > i_rel) sc[jt][r] = -1e30f;
        }
    }

    // online softmax update (fp32)
    float pm[4];
#pragma unroll
    for (int r = 0; r < 4; ++r) {
      float mx = fmaxf(fmaxf(sc[0][r], sc[1][r]), fmaxf(sc[2][r], sc[3][r]));
#pragma unroll
      for (int sh = 1; sh < 16; sh <<= 1) mx = fmaxf(mx, __shfl_xor(mx, sh));
      pm[r] = mx;
    }
    float psum[4];
#pragma unroll
    for (int r = 0; r < 4; ++r) {
      float mn = fmaxf(mrow[r], pm[r]);
      float sca = __expf(mrow[r] - mn);
      mrow[r] = mn;
      lrow[r] *= sca;
#pragma unroll
      for (int dt = 0; dt < 4; ++dt) ao[dt][r] *= sca;   // per-row rescale (FIXED)
      psum[r] = 0.f;
    }
#pragma unroll
    for (int jt = 0; jt < 4; ++jt) {
#pragma unroll
      for (int r = 0; r < 4; ++r) {
        float p = __expf(sc[jt][r] - mrow[r]);
        short pb = f2b(p);
        psum[r] += b2f(pb);                // sum the bf16-rounded P (unbiased O)
        int i = irow + r;
        int jj = jt * 16 + (l & 15);
        Ps[w][i * 64 + (jj ^ ((i & 7) << 3))] = pb;
      }
    }
#pragma unroll
    for (int r = 0; r < 4; ++r) {
      float s2 = psum[r];
#pragma unroll
      for (int sh = 1; sh < 16; sh <<= 1) s2 += __shfl_xor(s2, sh);
      lrow[r] += s2;
    }

    // O += P * V  (A = P from swizzled per-wave LDS, B = V^T tile)
#pragma unroll
    for (int ks2 = 0; ks2 < 2; ++ks2) {
      const int cb = ks2 * 64 + ((l >> 4) * 16);
      int pr = l & 15;
      short8 pf = *reinterpret_cast<const short8*>(
          reinterpret_cast<const char*>(Ps[w]) + pr * 128 + (cb ^ ((pr & 7) << 4)));
#pragma unroll
      for (int dt = 0; dt < 4; ++dt) {
        int vr = dt * 16 + (l & 15);
        short8 vf = *reinterpret_cast<const short8*>(
            reinterpret_cast<const char*>(Vs) + vr * 128 + (cb ^ ((vr & 7) << 4)));
        ao[dt] = __builtin_amdgcn_mfma_f32_16x16x32_bf16(pf, vf, ao[dt], 0, 0, 0);
      }
    }
    __syncthreads();
  }

  // write O as bf16 (B, N, H*D) for the output projection
  const int b = bh >> 4, h = bh & 15;
#pragma unroll
  for (int dt = 0; dt < 4; ++dt) {
#pragma unroll
    for (int r = 0; r < 4; ++r) {
      int n = q0 + w * 16 + irow + r;
      int col = h * 64 + dt * 16 + (l & 15);
      ob[((size_t)b * NSEQ + n) * DMODEL + col] = f2b(ao[dt][r] / lrow[r]);
    }
  }
}

// ---------------- launch ----------------
// Workspace layout (bytes):            total ~48.6 MB
//   0        xb   (4M bf16, 8MB)
//   8MB      wqb  (2MB)   10MB wkb   12MB wvb   14MB wob
//   16MB     qb   (8MB)   24MB kb    32MB vt    40MB ob
//   48MB     cs table (512KB)
extern "C" void kernel_launch(void* const* d_in, const int* in_sizes, int n_in,
                              void* d_out, int out_size, void* d_ws, size_t ws_size,
                              hipStream_t stream) {
  const float* x  = (const float*)d_in[0];
  const float* Wq = (const float*)d_in[1];
  const float* Wk = (const float*)d_in[2];
  const float* Wv = (const float*)d_in[3];
  const float* Wo = (const float*)d_in[4];
  const int*   pos = (const int*)d_in[5];
  float* out = (float*)d_out;
  char* ws = (char*)d_ws;

  short* xb  = (short*)(ws);
  short* wqb = (short*)(ws + ((size_t)8  << 20));
  short* wkb = (short*)(ws + ((size_t)10 << 20));
  short* wvb = (short*)(ws + ((size_t)12 << 20));
  short* wob = (short*)(ws + ((size_t)14 << 20));
  short* qb  = (short*)(ws + ((size_t)16 << 20));
  short* kb  = (short*)(ws + ((size_t)24 << 20));
  short* vt  = (short*)(ws + ((size_t)32 << 20));
  short* ob  = (short*)(ws + ((size_t)40 << 20));
  float* cs  = (float*)(ws + ((size_t)48 << 20));

  cvt_bf16<<<512, 256, 0, stream>>>(x,  xb,  (BSZ * NSEQ * DMODEL) / 4);
  cvt_bf16<<<256, 256, 0, stream>>>(Wq, wqb, (DMODEL * DMODEL) / 4);
  cvt_bf16<<<256, 256, 0, stream>>>(Wk, wkb, (DMODEL * DMODEL) / 4);
  cvt_bf16<<<256, 256, 0, stream>>>(Wv, wvb, (DMODEL * DMODEL) / 4);
  cvt_bf16<<<256, 256, 0, stream>>>(Wo, wob, (DMODEL * DMODEL) / 4);
  rope_table<<<(NSEQ * 32) / 256, 256, 0, stream>>>(pos, cs);

  gemm_qkv<<<dim3(MROWS / 128, 24), 256, 0, stream>>>(xb, wqb, wkb, wvb, cs, qb, kb, vt);
  attn<<<dim3(BSZ * NH, NSEQ / 64), 256, 0, stream>>>(qb, kb, vt, ob);
  gemm_out<<<dim3(MROWS / 128, DMODEL / 128), 256, 0, stream>>>(ob, wob, out);
}

// Round 4
// 164.397 us; speedup vs baseline: 1.1407x; 1.1407x over previous
//
#include <hip/hip_runtime.h>

// Problem constants (B=2, N=2048, d_model=1024, H=16, D=64)
#define DMODEL 1024
#define NSEQ   2048
#define BSZ    2
#define NH     16
#define HD     64
#define MROWS  (BSZ*NSEQ)   // 4096

using short8 = __attribute__((ext_vector_type(8))) short;
using f32x4  = __attribute__((ext_vector_type(4))) float;

__device__ __forceinline__ short f2b(float f) {
  unsigned u = __builtin_bit_cast(unsigned, f);
  u += 0x7fffu + ((u >> 16) & 1u);          // RNE
  return (short)(u >> 16);
}

__device__ __forceinline__ void load_lds16(const void* g, void* l) {
  __builtin_amdgcn_global_load_lds((const __attribute__((address_space(1))) unsigned int*)g,
                                   (__attribute__((address_space(3))) unsigned int*)l,
                                   16, 0, 0);
}

// ---------------- fp32 -> bf16 conversion ----------------
__global__ void cvt_bf16(const float* __restrict__ in, short* __restrict__ out, int n4) {
  int i = blockIdx.x * blockDim.x + threadIdx.x;
  int stride = gridDim.x * blockDim.x;
  for (; i < n4; i += stride) {
    float4 v = reinterpret_cast<const float4*>(in)[i];
    short4 r;
    r.x = f2b(v.x); r.y = f2b(v.y); r.z = f2b(v.z); r.w = f2b(v.w);
    reinterpret_cast<short4*>(out)[i] = r;
  }
}

// ---------------- RoPE cos/sin table (fp32, precise) ----------------
__global__ void rope_table(const int* __restrict__ pos, float* __restrict__ cs) {
  int idx = blockIdx.x * blockDim.x + threadIdx.x;   // n*32 + p
  if (idx >= NSEQ * 32) return;
  int n = idx >> 5, p = idx & 31;
  float inv = powf(10000.0f, -(float)(2 * p) / 64.0f);
  float ang = (float)pos[n] * inv;
  cs[idx * 2]     = cosf(ang);
  cs[idx * 2 + 1] = sinf(ang);
}

// ---------------- shared 128x128x(K=1024) bf16 MFMA GEMM core ----------------
__device__ __forceinline__ void gemm_core(const short* __restrict__ A,
                                          const short* __restrict__ Bw,
                                          int arow0, int bcol0,
                                          short* As, short* Bs,
                                          f32x4 (&acc)[4][4]) {
  const int t = threadIdx.x;
  const int l = t & 63;
  const int w = t >> 6;
  const int wr = (w >> 1) * 64;
  const int wc = (w & 1) * 64;
  const int srow = t >> 3;   // 0..31
  const int sc8  = t & 7;

#pragma unroll
  for (int mi = 0; mi < 4; ++mi)
#pragma unroll
    for (int ni = 0; ni < 4; ++ni) acc[mi][ni] = f32x4{0.f, 0.f, 0.f, 0.f};

  for (int kt = 0; kt < DMODEL / 64; ++kt) {
#pragma unroll
    for (int is = 0; is < 4; ++is) {
      int row = srow + is * 32;
      int c8 = sc8 ^ (row & 7);                    // pre-swizzled source
      load_lds16(A  + (size_t)(arow0 + row) * DMODEL + kt * 64 + c8 * 8,
                 As + w * 512 + is * 2048);
      load_lds16(Bw + (size_t)(bcol0 + row) * DMODEL + kt * 64 + c8 * 8,
                 Bs + w * 512 + is * 2048);
    }
    asm volatile("s_waitcnt vmcnt(0)" ::: "memory");
    __syncthreads();

#pragma unroll
    for (int ks = 0; ks < 2; ++ks) {
      short8 af[4], bf[4];
      const int cb = ks * 64 + ((l >> 4) * 16);    // byte col within 128B row
#pragma unroll
      for (int mi = 0; mi < 4; ++mi) {
        int rr = wr + mi * 16 + (l & 15);
        af[mi] = *reinterpret_cast<const short8*>(
            reinterpret_cast<const char*>(As) + rr * 128 + (cb ^ ((rr & 7) << 4)));
      }
#pragma unroll
      for (int ni = 0; ni < 4; ++ni) {
        int rr = wc + ni * 16 + (l & 15);
        bf[ni] = *reinterpret_cast<const short8*>(
            reinterpret_cast<const char*>(Bs) + rr * 128 + (cb ^ ((rr & 7) << 4)));
      }
#pragma unroll
      for (int mi = 0; mi < 4; ++mi)
#pragma unroll
        for (int ni = 0; ni < 4; ++ni)
          acc[mi][ni] = __builtin_amdgcn_mfma_f32_16x16x32_bf16(af[mi], bf[ni], acc[mi][ni], 0, 0, 0);
    }
    __syncthreads();
  }
}

// ---------------- QKV projection + fused RoPE epilogue ----------------
__global__ __launch_bounds__(256) void gemm_qkv(
    const short* __restrict__ xb,
    const short* __restrict__ wq, const short* __restrict__ wk, const short* __restrict__ wv,
    const float* __restrict__ cs,
    short* __restrict__ qb, short* __restrict__ kb, short* __restrict__ vt) {
  __shared__ short As[128 * 64];
  __shared__ short Bs[128 * 64];
  const int t = threadIdx.x;
  const int l = t & 63;
  const int w = t >> 6;
  const int wr = (w >> 1) * 64;
  const int wc = (w & 1) * 64;
  const int bx = blockIdx.x;
  const int by = blockIdx.y;
  const int proj = by >> 3;
  const int bcol0 = (by & 7) * 128;
  const int arow0 = bx * 128;
  const short* Bw = (proj == 0) ? wq : (proj == 1) ? wk : wv;

  f32x4 acc[4][4];
  gemm_core(xb, Bw, arow0, bcol0, As, Bs, acc);

#pragma unroll
  for (int mi = 0; mi < 4; ++mi) {
#pragma unroll
    for (int ni = 0; ni < 4; ++ni) {
#pragma unroll
      for (int r = 0; r < 4; ++r) {
        float v = acc[mi][ni][r];
        int m = arow0 + wr + mi * 16 + ((l >> 4) << 2) + r;
        int j = bcol0 + wc + ni * 16 + (l & 15);
        int n = m & (NSEQ - 1);
        int b = m >> 11;
        int h = j >> 6, d = j & 63, p = d >> 1;
        float pv = __shfl_xor(v, 1);              // partner column (j^1), same row
        if (proj < 2) {
          float c = cs[(n * 32 + p) * 2];
          float s = cs[(n * 32 + p) * 2 + 1];
          float res = (d & 1) ? (pv * s + v * c) : (v * c - pv * s);
          if (proj == 0) res *= 0.125f;           // fold 1/sqrt(D); exact pow2 in bf16
          short* dst = (proj == 0) ? qb : kb;
          dst[(((size_t)(b * NH + h)) * NSEQ + n) * HD + d] = f2b(res);
        } else {
          vt[(((size_t)(b * NH + h)) * HD + d) * NSEQ + n] = f2b(v);
        }
      }
    }
  }
}

// ---------------- output projection ----------------
__global__ __launch_bounds__(256) void gemm_out(
    const short* __restrict__ ob, const short* __restrict__ wo, float* __restrict__ out) {
  __shared__ short As[128 * 64];
  __shared__ short Bs[128 * 64];
  const int t = threadIdx.x;
  const int l = t & 63;
  const int w = t >> 6;
  const int wr = (w >> 1) * 64;
  const int wc = (w & 1) * 64;
  const int arow0 = blockIdx.x * 128;
  const int bcol0 = blockIdx.y * 128;

  f32x4 acc[4][4];
  gemm_core(ob, wo, arow0, bcol0, As, Bs, acc);

#pragma unroll
  for (int mi = 0; mi < 4; ++mi) {
#pragma unroll
    for (int ni = 0; ni < 4; ++ni) {
#pragma unroll
      for (int r = 0; r < 4; ++r) {
        int m = arow0 + wr + mi * 16 + ((l >> 4) << 2) + r;
        int j = bcol0 + wc + ni * 16 + (l & 15);
        out[(size_t)m * DMODEL + j] = acc[mi][ni][r];
      }
    }
  }
}

// ---------------- flash attention (causal, online softmax) ----------------
// grid (B*H=32, 16): triangle fold — block y handles q-tiles y and 31-y
// sequentially => uniform 33 KV-tiles per block (load balance).
// 4 waves; wave w owns Q rows qt*64 + w*16 .. +15.
// Per KV tile: S = Q*K^T (Q pre-scaled 1/8), defer-max online softmax
// (THR=8), P->bf16 via per-wave swizzled LDS, row-sum via ones-MFMA,
// PV via V^T tiles.
__global__ __launch_bounds__(256) void attn(
    const short* __restrict__ qb, const short* __restrict__ kb,
    const short* __restrict__ vt, short* __restrict__ ob) {
  __shared__ short Ks[64 * 64];
  __shared__ short Vs[64 * 64];
  __shared__ short Ps[4][16 * 64];
  const int t = threadIdx.x;
  const int l = t & 63;
  const int w = t >> 6;
  const int bh = blockIdx.x;
  const short* Q  = qb + (size_t)bh * NSEQ * HD;
  const short* Kg = kb + (size_t)bh * NSEQ * HD;
  const short* Vg = vt + (size_t)bh * HD * NSEQ;
  const int b = bh >> 4, h = bh & 15;

  const int srow = t >> 3;                // 0..31
  const int sc8  = t & 7;
  const int irow = (l >> 4) << 2;
  const float L2E = 1.44269504f;
  const short8 ones = {(short)0x3F80, (short)0x3F80, (short)0x3F80, (short)0x3F80,
                       (short)0x3F80, (short)0x3F80, (short)0x3F80, (short)0x3F80};

  for (int pass = 0; pass < 2; ++pass) {
    const int qt = pass ? (31 - blockIdx.y) : blockIdx.y;
    const int q0 = qt * 64;

    // Q fragments in registers (16 rows x 64 d per wave)
    short8 qf[2];
    {
      int qrow = q0 + w * 16 + (l & 15);
#pragma unroll
      for (int ks = 0; ks < 2; ++ks)
        qf[ks] = *reinterpret_cast<const short8*>(Q + (size_t)qrow * HD + ks * 32 + (l >> 4) * 8);
    }

    f32x4 ao[4];
#pragma unroll
    for (int dt = 0; dt < 4; ++dt) ao[dt] = f32x4{0.f, 0.f, 0.f, 0.f};
    f32x4 accl = f32x4{0.f, 0.f, 0.f, 0.f};          // row-sum accumulator (ones-MFMA)
    float mrow[4], ml2[4];
#pragma unroll
    for (int r = 0; r < 4; ++r) { mrow[r] = -1e30f; ml2[r] = -1.44e30f; }

    for (int tile = 0; tile <= qt; ++tile) {
      const int j0 = tile * 64;
#pragma unroll
      for (int is = 0; is < 2; ++is) {
        int row = srow + is * 32;
        int c8 = sc8 ^ (row & 7);
        load_lds16(Kg + (size_t)(j0 + row) * HD + c8 * 8, Ks + w * 512 + is * 2048);
        load_lds16(Vg + (size_t)row * NSEQ + j0 + c8 * 8, Vs + w * 512 + is * 2048);
      }
      asm volatile("s_waitcnt vmcnt(0)" ::: "memory");
      __syncthreads();

      // S = Q K^T (already scaled by 1/8 via Q)
      f32x4 sc[4];
#pragma unroll
      for (int jt = 0; jt < 4; ++jt) sc[jt] = f32x4{0.f, 0.f, 0.f, 0.f};
#pragma unroll
      for (int ks = 0; ks < 2; ++ks) {
        const int cb = ks * 64 + ((l >> 4) * 16);
#pragma unroll
        for (int jt = 0; jt < 4; ++jt) {
          int kr = jt * 16 + (l & 15);
          short8 kf = *reinterpret_cast<const short8*>(
              reinterpret_cast<const char*>(Ks) + kr * 128 + (cb ^ ((kr & 7) << 4)));
          sc[jt] = __builtin_amdgcn_mfma_f32_16x16x32_bf16(qf[ks], kf, sc[jt], 0, 0, 0);
        }
      }

      if (tile == qt) {                    // causal mask on diagonal tile
#pragma unroll
        for (int jt = 0; jt < 4; ++jt)
#pragma unroll
          for (int r = 0; r < 4; ++r) {
            int i_rel = w * 16 + irow + r;
            int jj = jt * 16 + (l & 15);
            if (jj > i_rel) sc[jt][r] = -1e30f;
          }
      }

      // row max (per r over 4 jt + 16-lane tree)
      float pm[4];
#pragma unroll
      for (int r = 0; r < 4; ++r) {
        float mx = fmaxf(fmaxf(sc[0][r], sc[1][r]), fmaxf(sc[2][r], sc[3][r]));
#pragma unroll
        for (int sh = 1; sh < 16; sh <<= 1) mx = fmaxf(mx, __shfl_xor(mx, sh));
        pm[r] = mx;
      }
      // defer-max: rescale only when max grew by > 8 (P bounded by e^8)
      bool need = (pm[0] > mrow[0] + 8.f) | (pm[1] > mrow[1] + 8.f) |
                  (pm[2] > mrow[2] + 8.f) | (pm[3] > mrow[3] + 8.f);
      if (__any(need)) {
#pragma unroll
        for (int r = 0; r < 4; ++r) {
          float mn  = fmaxf(mrow[r], pm[r]);
          float nl2 = mn * L2E;
          float sca = __builtin_amdgcn_exp2f(ml2[r] - nl2);
          mrow[r] = mn; ml2[r] = nl2;
#pragma unroll
          for (int dt = 0; dt < 4; ++dt) ao[dt][r] *= sca;
          accl[r] *= sca;
        }
      }
      // P = exp2(S*log2e - ml2), bf16, to per-wave swizzled LDS
#pragma unroll
      for (int jt = 0; jt < 4; ++jt) {
#pragma unroll
        for (int r = 0; r < 4; ++r) {
          float p = __builtin_amdgcn_exp2f(fmaf(sc[jt][r], L2E, -ml2[r]));
          int i = irow + r;
          int jj = jt * 16 + (l & 15);
          Ps[w][i * 64 + (jj ^ ((i & 7) << 3))] = f2b(p);
        }
      }

      // O += P*V ; row-sum += P*ones  (A = P from swizzled per-wave LDS)
#pragma unroll
      for (int ks2 = 0; ks2 < 2; ++ks2) {
        const int cb = ks2 * 64 + ((l >> 4) * 16);
        int pr = l & 15;
        short8 pf = *reinterpret_cast<const short8*>(
            reinterpret_cast<const char*>(Ps[w]) + pr * 128 + (cb ^ ((pr & 7) << 4)));
        accl = __builtin_amdgcn_mfma_f32_16x16x32_bf16(pf, ones, accl, 0, 0, 0);
#pragma unroll
        for (int dt = 0; dt < 4; ++dt) {
          int vr = dt * 16 + (l & 15);
          short8 vf = *reinterpret_cast<const short8*>(
              reinterpret_cast<const char*>(Vs) + vr * 128 + (cb ^ ((vr & 7) << 4)));
          ao[dt] = __builtin_amdgcn_mfma_f32_16x16x32_bf16(pf, vf, ao[dt], 0, 0, 0);
        }
      }
      __syncthreads();
    }

    // write O as bf16 (B, N, H*D) for the output projection
#pragma unroll
    for (int dt = 0; dt < 4; ++dt) {
#pragma unroll
      for (int r = 0; r < 4; ++r) {
        int n = q0 + w * 16 + irow + r;
        int col = h * 64 + dt * 16 + (l & 15);
        ob[((size_t)b * NSEQ + n) * DMODEL + col] = f2b(ao[dt][r] / accl[r]);
      }
    }
  }
}

// ---------------- launch ----------------
extern "C" void kernel_launch(void* const* d_in, const int* in_sizes, int n_in,
                              void* d_out, int out_size, void* d_ws, size_t ws_size,
                              hipStream_t stream) {
  const float* x  = (const float*)d_in[0];
  const float* Wq = (const float*)d_in[1];
  const float* Wk = (const float*)d_in[2];
  const float* Wv = (const float*)d_in[3];
  const float* Wo = (const float*)d_in[4];
  const int*   pos = (const int*)d_in[5];
  float* out = (float*)d_out;
  char* ws = (char*)d_ws;

  short* xb  = (short*)(ws);
  short* wqb = (short*)(ws + ((size_t)8  << 20));
  short* wkb = (short*)(ws + ((size_t)10 << 20));
  short* wvb = (short*)(ws + ((size_t)12 << 20));
  short* wob = (short*)(ws + ((size_t)14 << 20));
  short* qb  = (short*)(ws + ((size_t)16 << 20));
  short* kb  = (short*)(ws + ((size_t)24 << 20));
  short* vt  = (short*)(ws + ((size_t)32 << 20));
  short* ob  = (short*)(ws + ((size_t)40 << 20));
  float* cs  = (float*)(ws + ((size_t)48 << 20));

  cvt_bf16<<<512, 256, 0, stream>>>(x,  xb,  (BSZ * NSEQ * DMODEL) / 4);
  cvt_bf16<<<256, 256, 0, stream>>>(Wq, wqb, (DMODEL * DMODEL) / 4);
  cvt_bf16<<<256, 256, 0, stream>>>(Wk, wkb, (DMODEL * DMODEL) / 4);
  cvt_bf16<<<256, 256, 0, stream>>>(Wv, wvb, (DMODEL * DMODEL) / 4);
  cvt_bf16<<<256, 256, 0, stream>>>(Wo, wob, (DMODEL * DMODEL) / 4);
  rope_table<<<(NSEQ * 32) / 256, 256, 0, stream>>>(pos, cs);

  gemm_qkv<<<dim3(MROWS / 128, 24), 256, 0, stream>>>(xb, wqb, wkb, wvb, cs, qb, kb, vt);
  attn<<<dim3(BSZ * NH, NSEQ / 128), 256, 0, stream>>>(qb, kb, vt, ob);
  gemm_out<<<dim3(MROWS / 128, DMODEL / 128), 256, 0, stream>>>(ob, wob, out);
}

// Round 6
// 160.052 us; speedup vs baseline: 1.1717x; 1.0271x over previous
//
#include <hip/hip_runtime.h>

// Problem constants (B=2, N=2048, d_model=1024, H=16, D=64)
#define DMODEL 1024
#define NSEQ   2048
#define BSZ    2
#define NH     16
#define HD     64
#define MROWS  (BSZ*NSEQ)   // 4096

using short8 = __attribute__((ext_vector_type(8))) short;
using f32x4  = __attribute__((ext_vector_type(4))) float;

__device__ __forceinline__ short f2b(float f) {
  unsigned u = __builtin_bit_cast(unsigned, f);
  u += 0x7fffu + ((u >> 16) & 1u);          // RNE
  return (short)(u >> 16);
}

__device__ __forceinline__ void load_lds16(const void* g, void* l) {
  __builtin_amdgcn_global_load_lds((const __attribute__((address_space(1))) unsigned int*)g,
                                   (__attribute__((address_space(3))) unsigned int*)l,
                                   16, 0, 0);
}

// ---------------- fp32 -> bf16 conversion ----------------
__global__ void cvt_bf16(const float* __restrict__ in, short* __restrict__ out, int n4) {
  int i = blockIdx.x * blockDim.x + threadIdx.x;
  int stride = gridDim.x * blockDim.x;
  for (; i < n4; i += stride) {
    float4 v = reinterpret_cast<const float4*>(in)[i];
    short4 r;
    r.x = f2b(v.x); r.y = f2b(v.y); r.z = f2b(v.z); r.w = f2b(v.w);
    reinterpret_cast<short4*>(out)[i] = r;
  }
}

// ---------------- RoPE cos/sin table (fp32, precise) ----------------
__global__ void rope_table(const int* __restrict__ pos, float* __restrict__ cs) {
  int idx = blockIdx.x * blockDim.x + threadIdx.x;   // n*32 + p
  if (idx >= NSEQ * 32) return;
  int n = idx >> 5, p = idx & 31;
  float inv = powf(10000.0f, -(float)(2 * p) / 64.0f);
  float ang = (float)pos[n] * inv;
  cs[idx * 2]     = cosf(ang);
  cs[idx * 2 + 1] = sinf(ang);
}

// ---------------- shared 128x128x(K=1024) bf16 MFMA GEMM core ----------------
// 2-phase double-buffered (T3 minimum): STAGE(t+1) issued before compute(t),
// one vmcnt-draining barrier per K-step. LDS [2][128][64] per operand,
// T2 XOR-swizzle via pre-swizzled global source + swizzled ds_read.
__device__ __forceinline__ void gemm_core(const short* __restrict__ A,
                                          const short* __restrict__ Bw,
                                          int arow0, int bcol0,
                                          short* As, short* Bs,   // [2][128*64] each
                                          f32x4 (&acc)[4][4]) {
  const int t = threadIdx.x;
  const int l = t & 63;
  const int w = t >> 6;
  const int wr = (w >> 1) * 64;
  const int wc = (w & 1) * 64;
  const int srow = t >> 3;              // 0..31
  const int c8   = (t & 7) ^ (srow & 7);  // (row&7)==(srow&7) since rows step by 32

#pragma unroll
  for (int mi = 0; mi < 4; ++mi)
#pragma unroll
    for (int ni = 0; ni < 4; ++ni) acc[mi][ni] = f32x4{0.f, 0.f, 0.f, 0.f};

  auto STAGE = [&](int kt, int buf) {
#pragma unroll
    for (int is = 0; is < 4; ++is) {
      int row = srow + is * 32;
      load_lds16(A  + (size_t)(arow0 + row) * DMODEL + kt * 64 + c8 * 8,
                 As + buf * 8192 + w * 512 + is * 2048);
      load_lds16(Bw + (size_t)(bcol0 + row) * DMODEL + kt * 64 + c8 * 8,
                 Bs + buf * 8192 + w * 512 + is * 2048);
    }
  };

  STAGE(0, 0);
  __syncthreads();                      // drains vmcnt -> buf0 full
  int cur = 0;

  for (int kt = 0; kt < DMODEL / 64; ++kt) {
    if (kt + 1 < DMODEL / 64) STAGE(kt + 1, cur ^ 1);   // issue BEFORE compute

    const char* Ab = reinterpret_cast<const char*>(As + cur * 8192);
    const char* Bb = reinterpret_cast<const char*>(Bs + cur * 8192);
#pragma unroll
    for (int ks = 0; ks < 2; ++ks) {
      short8 af[4], bf[4];
      const int cb = ks * 64 + ((l >> 4) * 16);    // byte col within 128B row
#pragma unroll
      for (int mi = 0; mi < 4; ++mi) {
        int rr = wr + mi * 16 + (l & 15);
        af[mi] = *reinterpret_cast<const short8*>(Ab + rr * 128 + (cb ^ ((rr & 7) << 4)));
      }
#pragma unroll
      for (int ni = 0; ni < 4; ++ni) {
        int rr = wc + ni * 16 + (l & 15);
        bf[ni] = *reinterpret_cast<const short8*>(Bb + rr * 128 + (cb ^ ((rr & 7) << 4)));
      }
#pragma unroll
      for (int mi = 0; mi < 4; ++mi)
#pragma unroll
        for (int ni = 0; ni < 4; ++ni)
          acc[mi][ni] = __builtin_amdgcn_mfma_f32_16x16x32_bf16(af[mi], bf[ni], acc[mi][ni], 0, 0, 0);
    }
    if (kt + 1 < DMODEL / 64) {
      __syncthreads();                  // drain next-tile loads + protect buffers
      cur ^= 1;
    }
  }
}

// ---------------- QKV projection + fused RoPE epilogue ----------------
__global__ __launch_bounds__(256) void gemm_qkv(
    const short* __restrict__ xb,
    const short* __restrict__ wq, const short* __restrict__ wk, const short* __restrict__ wv,
    const float* __restrict__ cs,
    short* __restrict__ qb, short* __restrict__ kb, short* __restrict__ vt) {
  __shared__ short As[2 * 128 * 64];
  __shared__ short Bs[2 * 128 * 64];
  const int t = threadIdx.x;
  const int l = t & 63;
  const int w = t >> 6;
  const int wr = (w >> 1) * 64;
  const int wc = (w & 1) * 64;
  const int bx = blockIdx.x;
  const int by = blockIdx.y;
  const int proj = by >> 3;
  const int bcol0 = (by & 7) * 128;
  const int arow0 = bx * 128;
  const short* Bw = (proj == 0) ? wq : (proj == 1) ? wk : wv;

  f32x4 acc[4][4];
  gemm_core(xb, Bw, arow0, bcol0, As, Bs, acc);

#pragma unroll
  for (int mi = 0; mi < 4; ++mi) {
#pragma unroll
    for (int ni = 0; ni < 4; ++ni) {
#pragma unroll
      for (int r = 0; r < 4; ++r) {
        float v = acc[mi][ni][r];
        int m = arow0 + wr + mi * 16 + ((l >> 4) << 2) + r;
        int j = bcol0 + wc + ni * 16 + (l & 15);
        int n = m & (NSEQ - 1);
        int b = m >> 11;
        int h = j >> 6, d = j & 63, p = d >> 1;
        float pv = __shfl_xor(v, 1);              // partner column (j^1), same row
        if (proj < 2) {
          float c = cs[(n * 32 + p) * 2];
          float s = cs[(n * 32 + p) * 2 + 1];
          float res = (d & 1) ? (pv * s + v * c) : (v * c - pv * s);
          if (proj == 0) res *= 0.125f;           // fold 1/sqrt(D); exact pow2 in bf16
          short* dst = (proj == 0) ? qb : kb;
          dst[(((size_t)(b * NH + h)) * NSEQ + n) * HD + d] = f2b(res);
        } else {
          vt[(((size_t)(b * NH + h)) * HD + d) * NSEQ + n] = f2b(v);
        }
      }
    }
  }
}

// ---------------- output projection ----------------
__global__ __launch_bounds__(256) void gemm_out(
    const short* __restrict__ ob, const short* __restrict__ wo, float* __restrict__ out) {
  __shared__ short As[2 * 128 * 64];
  __shared__ short Bs[2 * 128 * 64];
  const int t = threadIdx.x;
  const int l = t & 63;
  const int w = t >> 6;
  const int wr = (w >> 1) * 64;
  const int wc = (w & 1) * 64;
  const int arow0 = blockIdx.x * 128;
  const int bcol0 = blockIdx.y * 128;

  f32x4 acc[4][4];
  gemm_core(ob, wo, arow0, bcol0, As, Bs, acc);

#pragma unroll
  for (int mi = 0; mi < 4; ++mi) {
#pragma unroll
    for (int ni = 0; ni < 4; ++ni) {
#pragma unroll
      for (int r = 0; r < 4; ++r) {
        int m = arow0 + wr + mi * 16 + ((l >> 4) << 2) + r;
        int j = bcol0 + wc + ni * 16 + (l & 15);
        out[(size_t)m * DMODEL + j] = acc[mi][ni][r];
      }
    }
  }
}

// ---------------- flash attention (causal, online softmax) ----------------
// grid (B*H=32, 16): triangle fold — block y handles q-tiles y and 31-y.
// 2-phase double-buffered K/V staging; defer-max online softmax (THR=8);
// P->bf16 via per-wave swizzled LDS; row-sum via ones-MFMA; PV via V^T tiles.
__global__ __launch_bounds__(256) void attn(
    const short* __restrict__ qb, const short* __restrict__ kb,
    const short* __restrict__ vt, short* __restrict__ ob) {
  __shared__ short Ks[2 * 64 * 64];
  __shared__ short Vs[2 * 64 * 64];
  __shared__ short Ps[4][16 * 64];
  const int t = threadIdx.x;
  const int l = t & 63;
  const int w = t >> 6;
  const int bh = blockIdx.x;
  const short* Q  = qb + (size_t)bh * NSEQ * HD;
  const short* Kg = kb + (size_t)bh * NSEQ * HD;
  const short* Vg = vt + (size_t)bh * HD * NSEQ;
  const int b = bh >> 4, h = bh & 15;

  const int srow = t >> 3;                // 0..31
  const int c8   = (t & 7) ^ (srow & 7);  // rows step by 32 -> (row&7) const
  const int irow = (l >> 4) << 2;
  const float L2E = 1.44269504f;
  const short8 ones = {(short)0x3F80, (short)0x3F80, (short)0x3F80, (short)0x3F80,
                       (short)0x3F80, (short)0x3F80, (short)0x3F80, (short)0x3F80};

  auto STAGEA = [&](int tile, int buf) {
    int j0 = tile * 64;
#pragma unroll
    for (int is = 0; is < 2; ++is) {
      int row = srow + is * 32;
      load_lds16(Kg + (size_t)(j0 + row) * HD + c8 * 8, Ks + buf * 4096 + w * 512 + is * 2048);
      load_lds16(Vg + (size_t)row * NSEQ + j0 + c8 * 8, Vs + buf * 4096 + w * 512 + is * 2048);
    }
  };

  int cur = 0;
  for (int pass = 0; pass < 2; ++pass) {
    const int qt = pass ? (31 - blockIdx.y) : blockIdx.y;
    const int q0 = qt * 64;

    // Q fragments in registers (16 rows x 64 d per wave)
    short8 qf[2];
    {
      int qrow = q0 + w * 16 + (l & 15);
#pragma unroll
      for (int ks = 0; ks < 2; ++ks)
        qf[ks] = *reinterpret_cast<const short8*>(Q + (size_t)qrow * HD + ks * 32 + (l >> 4) * 8);
    }

    f32x4 ao[4];
#pragma unroll
    for (int dt = 0; dt < 4; ++dt) ao[dt] = f32x4{0.f, 0.f, 0.f, 0.f};
    f32x4 accl = f32x4{0.f, 0.f, 0.f, 0.f};          // row-sum accumulator (ones-MFMA)
    float mrow[4], ml2[4];
#pragma unroll
    for (int r = 0; r < 4; ++r) { mrow[r] = -1e30f; ml2[r] = -1.44e30f; }

    STAGEA(0, cur);
    __syncthreads();                       // buf[cur] full

    for (int tile = 0; tile <= qt; ++tile) {
      if (tile < qt) STAGEA(tile + 1, cur ^ 1);   // issue BEFORE compute

      const char* Kb = reinterpret_cast<const char*>(Ks + cur * 4096);
      const char* Vb = reinterpret_cast<const char*>(Vs + cur * 4096);

      // S = Q K^T (already scaled by 1/8 via Q)
      f32x4 sc[4];
#pragma unroll
      for (int jt = 0; jt < 4; ++jt) sc[jt] = f32x4{0.f, 0.f, 0.f, 0.f};
#pragma unroll
      for (int ks = 0; ks < 2; ++ks) {
        const int cb = ks * 64 + ((l >> 4) * 16);
#pragma unroll
        for (int jt = 0; jt < 4; ++jt) {
          int kr = jt * 16 + (l & 15);
          short8 kf = *reinterpret_cast<const short8*>(Kb + kr * 128 + (cb ^ ((kr & 7) << 4)));
          sc[jt] = __builtin_amdgcn_mfma_f32_16x16x32_bf16(qf[ks], kf, sc[jt], 0, 0, 0);
        }
      }

      if (tile == qt) {                    // causal mask on diagonal tile
#pragma unroll
        for (int jt = 0; jt < 4; ++jt)
#pragma unroll
          for (int r = 0; r < 4; ++r) {
            int i_rel = w * 16 + irow + r;
            int jj = jt * 16 + (l & 15);
            if (jj > i_rel) sc[jt][r] = -1e30f;
          }
      }

      // row max (per r over 4 jt + 16-lane tree)
      float pm[4];
#pragma unroll
      for (int r = 0; r < 4; ++r) {
        float mx = fmaxf(fmaxf(sc[0][r], sc[1][r]), fmaxf(sc[2][r], sc[3][r]));
#pragma unroll
        for (int sh = 1; sh < 16; sh <<= 1) mx = fmaxf(mx, __shfl_xor(mx, sh));
        pm[r] = mx;
      }
      // defer-max: rescale only when max grew by > 8 (P bounded by e^8)
      bool need = (pm[0] > mrow[0] + 8.f) | (pm[1] > mrow[1] + 8.f) |
                  (pm[2] > mrow[2] + 8.f) | (pm[3] > mrow[3] + 8.f);
      if (__any(need)) {
#pragma unroll
        for (int r = 0; r < 4; ++r) {
          float mn  = fmaxf(mrow[r], pm[r]);
          float nl2 = mn * L2E;
          float sca = __builtin_amdgcn_exp2f(ml2[r] - nl2);
          mrow[r] = mn; ml2[r] = nl2;
#pragma unroll
          for (int dt = 0; dt < 4; ++dt) ao[dt][r] *= sca;
          accl[r] *= sca;
        }
      }
      // P = exp2(S*log2e - ml2), bf16, to per-wave swizzled LDS
#pragma unroll
      for (int jt = 0; jt < 4; ++jt) {
#pragma unroll
        for (int r = 0; r < 4; ++r) {
          float p = __builtin_amdgcn_exp2f(fmaf(sc[jt][r], L2E, -ml2[r]));
          int i = irow + r;
          int jj = jt * 16 + (l & 15);
          Ps[w][i * 64 + (jj ^ ((i & 7) << 3))] = f2b(p);
        }
      }

      // O += P*V ; row-sum += P*ones  (A = P from swizzled per-wave LDS)
#pragma unroll
      for (int ks2 = 0; ks2 < 2; ++ks2) {
        const int cb = ks2 * 64 + ((l >> 4) * 16);
        int pr = l & 15;
        short8 pf = *reinterpret_cast<const short8*>(
            reinterpret_cast<const char*>(Ps[w]) + pr * 128 + (cb ^ ((pr & 7) << 4)));
        accl = __builtin_amdgcn_mfma_f32_16x16x32_bf16(pf, ones, accl, 0, 0, 0);
#pragma unroll
        for (int dt = 0; dt < 4; ++dt) {
          int vr = dt * 16 + (l & 15);
          short8 vf = *reinterpret_cast<const short8*>(Vb + vr * 128 + (cb ^ ((vr & 7) << 4)));
          ao[dt] = __builtin_amdgcn_mfma_f32_16x16x32_bf16(pf, vf, ao[dt], 0, 0, 0);
        }
      }
      __syncthreads();                     // drain next-tile loads; protect buffers
      cur ^= 1;
    }

    // write O as bf16 (B, N, H*D) for the output projection
#pragma unroll
    for (int dt = 0; dt < 4; ++dt) {
#pragma unroll
      for (int r = 0; r < 4; ++r) {
        int n = q0 + w * 16 + irow + r;
        int col = h * 64 + dt * 16 + (l & 15);
        ob[((size_t)b * NSEQ + n) * DMODEL + col] = f2b(ao[dt][r] / accl[r]);
      }
    }
  }
}

// ---------------- launch ----------------
extern "C" void kernel_launch(void* const* d_in, const int* in_sizes, int n_in,
                              void* d_out, int out_size, void* d_ws, size_t ws_size,
                              hipStream_t stream) {
  const float* x  = (const float*)d_in[0];
  const float* Wq = (const float*)d_in[1];
  const float* Wk = (const float*)d_in[2];
  const float* Wv = (const float*)d_in[3];
  const float* Wo = (const float*)d_in[4];
  const int*   pos = (const int*)d_in[5];
  float* out = (float*)d_out;
  char* ws = (char*)d_ws;

  short* xb  = (short*)(ws);
  short* wqb = (short*)(ws + ((size_t)8  << 20));
  short* wkb = (short*)(ws + ((size_t)10 << 20));
  short* wvb = (short*)(ws + ((size_t)12 << 20));
  short* wob = (short*)(ws + ((size_t)14 << 20));
  short* qb  = (short*)(ws + ((size_t)16 << 20));
  short* kb  = (short*)(ws + ((size_t)24 << 20));
  short* vt  = (short*)(ws + ((size_t)32 << 20));
  short* ob  = (short*)(ws + ((size_t)40 << 20));
  float* cs  = (float*)(ws + ((size_t)48 << 20));

  cvt_bf16<<<512, 256, 0, stream>>>(x,  xb,  (BSZ * NSEQ * DMODEL) / 4);
  cvt_bf16<<<256, 256, 0, stream>>>(Wq, wqb, (DMODEL * DMODEL) / 4);
  cvt_bf16<<<256, 256, 0, stream>>>(Wk, wkb, (DMODEL * DMODEL) / 4);
  cvt_bf16<<<256, 256, 0, stream>>>(Wv, wvb, (DMODEL * DMODEL) / 4);
  cvt_bf16<<<256, 256, 0, stream>>>(Wo, wob, (DMODEL * DMODEL) / 4);
  rope_table<<<(NSEQ * 32) / 256, 256, 0, stream>>>(pos, cs);

  gemm_qkv<<<dim3(MROWS / 128, 24), 256, 0, stream>>>(xb, wqb, wkb, wvb, cs, qb, kb, vt);
  attn<<<dim3(BSZ * NH, NSEQ / 128), 256, 0, stream>>>(qb, kb, vt, ob);
  gemm_out<<<dim3(MROWS / 128, DMODEL / 128), 256, 0, stream>>>(ob, wob, out);
}